// Round 18
// baseline (30.748 us; speedup 1.0000x reference)
//
#include <hip/hip_runtime.h>

#define EPS 1e-4f
#define INVN (1.0f/512.0f)

// Two kernels, both REGULAR launches:
//  K1 embed (256 x 512, register-PREFETCH staging): ALL global reads (weights, x=eo/po,
//     y=emb_in AND pad unconditionally, mask probe) issued up front into registers ->
//     one MLP wave, one vmcnt wait; y is selected IN-REGISTER after the mask resolve
//     (r14's ternary-load forced a serialized HBM round trip after the mask sync).
//     Values/orders identical to r14 -> bit-identical output. Block 0 zeroes barrier slots.
//  K2 sinkhorn (256 x 512, ONE barrier, byte-identical r17): cost->K_sh + block-local
//     S_est (row-rescaling invariance: u0 absorbs per-row-block scale exactly) ->
//     exp+u0+colparts -> bar -> v1 -> P = u0*K*v1.
//
// ws layout (bytes):
//   [0, 2048)         barrier one-shot slots (zeroed by K1 blk0): batch b at 256*b,
//                     cnt @ +0, flag @ +128
//   [8192, 532480)    aG [4096][32] f32  == alias ==  parts_A [8][32][512]
//   [532480, 1056768) bvG [4096][32] f32  (read only in K2 phase a)

__device__ __forceinline__ void store_f32_cg(float* p, float v) {
  asm volatile("global_store_dword %0, %1, off sc0 sc1" :: "v"(p), "v"(v) : "memory");
}

// 8 float4 at 2048-byte row stride (k-slices of parts), one wait.
__device__ __forceinline__ void load8x4_s2k_cg(const float* p1, const float* p2, float4* o) {
  asm volatile(
      "global_load_dwordx4 %0, %8, off offset:-4096 sc0 sc1\n\t"
      "global_load_dwordx4 %1, %8, off offset:-2048 sc0 sc1\n\t"
      "global_load_dwordx4 %2, %8, off sc0 sc1\n\t"
      "global_load_dwordx4 %3, %8, off offset:2048 sc0 sc1\n\t"
      "global_load_dwordx4 %4, %9, off offset:-4096 sc0 sc1\n\t"
      "global_load_dwordx4 %5, %9, off offset:-2048 sc0 sc1\n\t"
      "global_load_dwordx4 %6, %9, off sc0 sc1\n\t"
      "global_load_dwordx4 %7, %9, off offset:2048 sc0 sc1\n\t"
      "s_waitcnt vmcnt(0)"
      : "=&v"(o[0]), "=&v"(o[1]), "=&v"(o[2]), "=&v"(o[3]),
        "=&v"(o[4]), "=&v"(o[5]), "=&v"(o[6]), "=&v"(o[7])
      : "v"(p1), "v"(p2)
      : "memory");
}

__device__ __forceinline__ void batch_barrier(int* cnt, int* flag) {
  asm volatile("s_waitcnt vmcnt(0)" ::: "memory");   // drain write-through stores to LLC
  __syncthreads();
  if (threadIdx.x == 0) {
    int prev = __hip_atomic_fetch_add(cnt, 1, __ATOMIC_RELAXED, __HIP_MEMORY_SCOPE_AGENT);
    if (prev == 31) {
      __hip_atomic_store(flag, 1, __ATOMIC_RELAXED, __HIP_MEMORY_SCOPE_AGENT);
    } else {
      while (__hip_atomic_load(flag, __ATOMIC_RELAXED, __HIP_MEMORY_SCOPE_AGENT) == 0) {}
    }
  }
  __syncthreads();
}

// ---- Kernel 1: embed GEMVs. 256 blocks x 512 threads, block = 16 nodes. ----
__global__ void __launch_bounds__(512)
embed_kernel(const float* __restrict__ emb_in, const void* __restrict__ maskp,
             const float* __restrict__ emb_out, const float* __restrict__ pad,
             const float* __restrict__ pos, const float* __restrict__ Win,
             const float* __restrict__ bin, const float* __restrict__ Wout,
             const float* __restrict__ bout,
             float* __restrict__ aG, float* __restrict__ bvG,
             char* __restrict__ ws) {
  const int t = threadIdx.x, blk = blockIdx.x;
  __shared__ float Wo_lds[8192];        // Wout [256][32], 32 KB
  __shared__ float Wi_lds[8192];        // Win  [256][32], 32 KB
  __shared__ float x_lds[16 * 260];     // (emb_out+pos)[n][d], pad 260
  __shared__ float y_lds[16 * 260];     // (emb_in|pad)[n][d]
  __shared__ float red_lds[7 * 64 * 20];// dh-reduce, 35 KB, stride 20 (16B-aligned)
  __shared__ unsigned dsh[2];
  __shared__ int mv_sh[16];

  if (blk == 0) store_f32_cg((float*)(ws + 4 * t), 0.0f);  // t<512 covers [0,2048)
  if (t < 2) dsh[t] = 0u;

  // ---- register prefetch: ALL global reads issued here (one MLP wave) ----
  float4 wo_r[4], wi_r[4];
#pragma unroll
  for (int k = 0; k < 4; ++k) {
    int i4 = k * 512 + t;               // 0..2047
    wo_r[k] = ((const float4*)Wout)[i4];
    wi_r[k] = ((const float4*)Win)[i4];
  }
  const float4* eo4  = (const float4*)(emb_out + (size_t)blk * 16 * 256);
  const float4* po4  = (const float4*)(pos + (size_t)((blk * 16) & 511) * 256);
  const float4* ein4 = (const float4*)(emb_in + (size_t)blk * 16 * 256);
  const float4* pad4 = (const float4*)pad;
  float4 eo_r[2], po_r[2], yi_r[2], pa_r[2];
#pragma unroll
  for (int k = 0; k < 2; ++k) {
    int i4 = k * 512 + t;               // 0..1023
    eo_r[k] = eo4[i4];
    po_r[k] = po4[i4];
    yi_r[k] = ein4[i4];                 // unconditional (always in-bounds)
    pa_r[k] = pad4[i4 & 63];            // unconditional (pad = 64 f4)
  }
  uint4 m4 = make_uint4(0, 0, 0, 0);
  if (t < 256) m4 = ((const uint4*)maskp)[t];   // first 4096 B (safe for all dtypes)

  __syncthreads();                      // dsh zeroed
  if (t < 256) {
    // mask element-size detect (dword-wise): bool(1B): any byte i%4!=0 nonzero;
    // int32: low byte of odd dwords nonzero; else int64.
    unsigned orb = (m4.x | m4.y | m4.z | m4.w) & 0xFFFFFF00u;
    unsigned orc = (m4.y | m4.w) & 0xFFu;
    if (orb) atomicOr(&dsh[0], 1u);
    if (orc) atomicOr(&dsh[1], 1u);
  }
  // write W and x LDS (mask-independent) while mask resolution proceeds
#pragma unroll
  for (int k = 0; k < 4; ++k) {
    int i4 = k * 512 + t;
    ((float4*)Wo_lds)[i4] = wo_r[k];
    ((float4*)Wi_lds)[i4] = wi_r[k];
  }
#pragma unroll
  for (int k = 0; k < 2; ++k) {
    int i4 = k * 512 + t;
    int n = i4 >> 6, dc = i4 & 63;
    *(float4*)&x_lds[n * 260 + dc * 4] =
        make_float4(eo_r[k].x + po_r[k].x, eo_r[k].y + po_r[k].y,
                    eo_r[k].z + po_r[k].z, eo_r[k].w + po_r[k].w);
  }
  __syncthreads();                      // dsh ready
  if (t < 16) {
    int g = blk * 16 + t;
    int mv;
    if (dsh[0])      mv = ((const unsigned char*)maskp)[g];       // L2-warm
    else if (dsh[1]) mv = ((const int*)maskp)[g];
    else             mv = (int)(((const long long*)maskp)[g] != 0);
    mv_sh[t] = mv;
  }
  __syncthreads();
#pragma unroll
  for (int k = 0; k < 2; ++k) {         // y select IN-REGISTER, then LDS write
    int i4 = k * 512 + t;
    int n = i4 >> 6, dc = i4 & 63;
    *(float4*)&y_lds[n * 260 + dc * 4] = mv_sh[n] ? pa_r[k] : yi_r[k];
  }
  __syncthreads();

  const int dh = t >> 6, lane = t & 63;
  const int np = lane >> 3, mq = lane & 7;
  const int dbase = dh * 32;
  float aA0[4] = {0,0,0,0}, aA1[4] = {0,0,0,0};
  float aB0[4] = {0,0,0,0}, aB1[4] = {0,0,0,0};
  const float* x0p = &x_lds[(2 * np) * 260 + dbase];
  const float* x1p = x0p + 260;
  const float* y0p = &y_lds[(2 * np) * 260 + dbase];
  const float* y1p = y0p + 260;
  const float* Wob = &Wo_lds[dbase * 32 + 4 * mq];
  const float* Wib = &Wi_lds[dbase * 32 + 4 * mq];
  for (int it = 0; it < 8; ++it) {
    int dd = it * 4;
    float4 x0 = *(const float4*)(x0p + dd);
    float4 x1 = *(const float4*)(x1p + dd);
    float4 y0 = *(const float4*)(y0p + dd);
    float4 y1 = *(const float4*)(y1p + dd);
#pragma unroll
    for (int j = 0; j < 4; ++j) {
      float4 wo = *(const float4*)(Wob + (dd + j) * 32);
      float4 wi = *(const float4*)(Wib + (dd + j) * 32);
      float xs0 = ((const float*)&x0)[j], xs1 = ((const float*)&x1)[j];
      float ys0 = ((const float*)&y0)[j], ys1 = ((const float*)&y1)[j];
#pragma unroll
      for (int q = 0; q < 4; ++q) {
        float woq = ((const float*)&wo)[q], wiq = ((const float*)&wi)[q];
        aA0[q] = fmaf(xs0, woq, aA0[q]);
        aA1[q] = fmaf(xs1, woq, aA1[q]);
        aB0[q] = fmaf(ys0, wiq, aB0[q]);
        aB1[q] = fmaf(ys1, wiq, aB1[q]);
      }
    }
  }
  __syncthreads();                      // all x/y/W reads done
  if (dh != 0) {
    float* rp = &red_lds[((dh - 1) * 64 + lane) * 20];
    *(float4*)&rp[0]  = *(float4*)&aA0[0];
    *(float4*)&rp[4]  = *(float4*)&aA1[0];
    *(float4*)&rp[8]  = *(float4*)&aB0[0];
    *(float4*)&rp[12] = *(float4*)&aB1[0];
  }
  __syncthreads();
  if (dh == 0) {
#pragma unroll
    for (int k = 0; k < 7; ++k) {       // add dh1..dh7 in d-order
      const float* rp = &red_lds[(k * 64 + lane) * 20];
      float4 pa0 = *(const float4*)&rp[0];
      float4 pa1 = *(const float4*)&rp[4];
      float4 pb0 = *(const float4*)&rp[8];
      float4 pb1 = *(const float4*)&rp[12];
      aA0[0] += pa0.x; aA0[1] += pa0.y; aA0[2] += pa0.z; aA0[3] += pa0.w;
      aA1[0] += pa1.x; aA1[1] += pa1.y; aA1[2] += pa1.z; aA1[3] += pa1.w;
      aB0[0] += pb0.x; aB0[1] += pb0.y; aB0[2] += pb0.z; aB0[3] += pb0.w;
      aB1[0] += pb1.x; aB1[1] += pb1.y; aB1[2] += pb1.z; aB1[3] += pb1.w;
    }
    float4 bo = *(const float4*)&bout[4 * mq];
    float4 bi = *(const float4*)&bin[4 * mq];
    const int g0 = blk * 16 + 2 * np;
    *(float4*)&aG[(size_t)g0 * 32 + 4 * mq] =
        make_float4(aA0[0] + bo.x, aA0[1] + bo.y, aA0[2] + bo.z, aA0[3] + bo.w);
    *(float4*)&aG[(size_t)(g0 + 1) * 32 + 4 * mq] =
        make_float4(aA1[0] + bo.x, aA1[1] + bo.y, aA1[2] + bo.z, aA1[3] + bo.w);
    *(float4*)&bvG[(size_t)g0 * 32 + 4 * mq] =
        make_float4(aB0[0] + bi.x, aB0[1] + bi.y, aB0[2] + bi.z, aB0[3] + bi.w);
    *(float4*)&bvG[(size_t)(g0 + 1) * 32 + 4 * mq] =
        make_float4(aB1[0] + bi.x, aB1[1] + bi.y, aB1[2] + bi.z, aB1[3] + bi.w);
  }
}

// ---- Kernel 2: cost + 1-iter Sinkhorn + P. 256 blocks x 512 threads. ONE barrier. ----
__global__ void __launch_bounds__(512)
sinkhorn_main(float* __restrict__ P, char* __restrict__ ws) {
  const int t = threadIdx.x;
  const int blk = blockIdx.x;
  const int b = blk & 7, loc = blk >> 3;
  const int r0 = loc * 16;
  const int w = t >> 6, lane = t & 63;

  int* cnts  = (int*)(ws + 256 * b);
  int* flags = (int*)(ws + 256 * b + 128);
  float* aG      = (float*)(ws + 8192);
  float* partsA  = (float*)(ws + 8192);
  float* bvG     = (float*)(ws + 532480);

  __shared__ float K_sh[16][512];
  __shared__ float scratch_sh[8][512];
  __shared__ float v_sh[512];
  __shared__ float a_sh[16][32];
  __shared__ float red_sh[8];
  __shared__ float sv_sh;

  // ---- Phase a: stage own a-rows + own bv column (plain cached loads; K1->K2
  //      dispatch boundary provides coherence) ----
  float bva[32];
  {
    const float4* bj = (const float4*)(bvG + ((size_t)(b * 512) + t) * 32);
    float4 bq0 = bj[0], bq1 = bj[1], bq2 = bj[2], bq3 = bj[3];
    float4 bq4 = bj[4], bq5 = bj[5], bq6 = bj[6], bq7 = bj[7];
    ((float*)a_sh)[t] = aG[(size_t)(b * 512 + r0) * 32 + t];
    bva[0]=bq0.x; bva[1]=bq0.y; bva[2]=bq0.z; bva[3]=bq0.w;
    bva[4]=bq1.x; bva[5]=bq1.y; bva[6]=bq1.z; bva[7]=bq1.w;
    bva[8]=bq2.x; bva[9]=bq2.y; bva[10]=bq2.z; bva[11]=bq2.w;
    bva[12]=bq3.x; bva[13]=bq3.y; bva[14]=bq3.z; bva[15]=bq3.w;
    bva[16]=bq4.x; bva[17]=bq4.y; bva[18]=bq4.z; bva[19]=bq4.w;
    bva[20]=bq5.x; bva[21]=bq5.y; bva[22]=bq5.z; bva[23]=bq5.w;
    bva[24]=bq6.x; bva[25]=bq6.y; bva[26]=bq6.z; bva[27]=bq6.w;
    bva[28]=bq7.x; bva[29]=bq7.y; bva[30]=bq7.z; bva[31]=bq7.w;
  }
  __syncthreads();

  // ---- Phase b: cost -> K_sh; BLOCK-LOCAL S estimate (row-rescaling invariance) ----
  {
    float csum = 0.f;
    for (int r = 0; r < 16; ++r) {
      const float4* ar4 = (const float4*)&a_sh[r][0];   // LDS broadcast reads
      float c0 = 0.f;
#pragma unroll
      for (int q = 0; q < 8; ++q) {
        float4 av = ar4[q];
        c0 += fabsf(av.x - bva[q * 4 + 0]) + fabsf(av.y - bva[q * 4 + 1])
            + fabsf(av.z - bva[q * 4 + 2]) + fabsf(av.w - bva[q * 4 + 3]);
      }
      K_sh[r][t] = c0;
      csum += c0;
    }
#pragma unroll
    for (int off = 1; off < 64; off <<= 1) csum += __shfl_xor(csum, off);
    if (lane == 0) red_sh[w] = csum;
    __syncthreads();
    if (t == 0) {
      float s = 0.f;
#pragma unroll
      for (int k = 0; k < 8; ++k) s += red_sh[k];
      sv_sh = -1.0f / (EPS * 32.0f * s);    // S_est = 32 x block sum
    }
  }
  __syncthreads();
  const float sv = sv_sh;

  float u_last[2];
  const int w2 = t >> 7, idx = t & 127;
  float* partrowA = partsA + ((size_t)(b * 32) + loc) * 512;
  const float* vpA1 = partsA + (size_t)b * 32 * 512 + (size_t)(w2 * 8) * 512 + idx * 4 + 1024;
  const float* vpA2 = vpA1 + 2048;

  // ---- Phase c: K = exp(C*sv), u0 (v==1), column partials -> parts_A ----
  {
    float colacc[8] = {0, 0, 0, 0, 0, 0, 0, 0};
#pragma unroll
    for (int rr = 0; rr < 2; ++rr) {
      int r = 2 * w + rr;
      float4 c0 = *(float4*)&K_sh[r][4 * lane];
      float4 c1 = *(float4*)&K_sh[r][256 + 4 * lane];
      float kv[8];
      kv[0] = __expf(c0.x * sv); kv[1] = __expf(c0.y * sv);
      kv[2] = __expf(c0.z * sv); kv[3] = __expf(c0.w * sv);
      kv[4] = __expf(c1.x * sv); kv[5] = __expf(c1.y * sv);
      kv[6] = __expf(c1.z * sv); kv[7] = __expf(c1.w * sv);
      *(float4*)&K_sh[r][4 * lane]       = make_float4(kv[0], kv[1], kv[2], kv[3]);
      *(float4*)&K_sh[r][256 + 4 * lane] = make_float4(kv[4], kv[5], kv[6], kv[7]);
      float s = kv[0] + kv[1] + kv[2] + kv[3] + kv[4] + kv[5] + kv[6] + kv[7];
#pragma unroll
      for (int off = 1; off < 64; off <<= 1) s += __shfl_xor(s, off);
      float uu = INVN / s;
      u_last[rr] = uu;
#pragma unroll
      for (int q = 0; q < 8; ++q) colacc[q] = fmaf(kv[q], uu, colacc[q]);
    }
    *(float4*)&scratch_sh[w][4 * lane]       = make_float4(colacc[0], colacc[1], colacc[2], colacc[3]);
    *(float4*)&scratch_sh[w][256 + 4 * lane] = make_float4(colacc[4], colacc[5], colacc[6], colacc[7]);
    __syncthreads();
    float s0 = 0.f;
#pragma unroll
    for (int k = 0; k < 8; ++k) s0 += scratch_sh[k][t];
    store_f32_cg(partrowA + t, s0);
  }
  batch_barrier(&cnts[0], &flags[0]);       // the ONLY barrier: parts_A ready

  // ---- Phase d: v1 from parts_A; P = u0 * K * v1 ----
  {
    float4 o[8];
    load8x4_s2k_cg(vpA1, vpA2, o);
    float4 acc = o[0];
    acc.x += o[1].x + o[2].x + o[3].x + o[4].x + o[5].x + o[6].x + o[7].x;
    acc.y += o[1].y + o[2].y + o[3].y + o[4].y + o[5].y + o[6].y + o[7].y;
    acc.z += o[1].z + o[2].z + o[3].z + o[4].z + o[5].z + o[6].z + o[7].z;
    acc.w += o[1].w + o[2].w + o[3].w + o[4].w + o[5].w + o[6].w + o[7].w;
    *(float4*)&scratch_sh[w2][4 * idx] = acc;
  }
  __syncthreads();
  v_sh[t] = INVN / (scratch_sh[0][t] + scratch_sh[1][t] + scratch_sh[2][t] + scratch_sh[3][t]);
  __syncthreads();
  {
    float4 v0 = *(float4*)&v_sh[4 * lane];
    float4 v1 = *(float4*)&v_sh[256 + 4 * lane];
#pragma unroll
    for (int rr = 0; rr < 2; ++rr) {
      int r = 2 * w + rr;
      float uu = u_last[rr];
      float4 k0 = *(float4*)&K_sh[r][4 * lane];
      float4 k1 = *(float4*)&K_sh[r][256 + 4 * lane];
      float4 o0 = make_float4(uu * k0.x * v0.x, uu * k0.y * v0.y,
                              uu * k0.z * v0.z, uu * k0.w * v0.w);
      float4 o1 = make_float4(uu * k1.x * v1.x, uu * k1.y * v1.y,
                              uu * k1.z * v1.z, uu * k1.w * v1.w);
      float* Prow = P + ((size_t)(b * 512) + r0 + r) * 512;
      *(float4*)(Prow + 4 * lane)       = o0;
      *(float4*)(Prow + 256 + 4 * lane) = o1;
    }
  }
}

extern "C" void kernel_launch(void* const* d_in, const int* in_sizes, int n_in,
                              void* d_out, int out_size, void* d_ws, size_t ws_size,
                              hipStream_t stream) {
  const float* emb_in  = (const float*)d_in[0];
  const void*  maskp   = d_in[1];
  const float* emb_out = (const float*)d_in[2];
  const float* pad     = (const float*)d_in[3];
  const float* pos     = (const float*)d_in[4];
  const float* Win     = (const float*)d_in[5];
  const float* bin     = (const float*)d_in[6];
  const float* Wout    = (const float*)d_in[7];
  const float* bout    = (const float*)d_in[8];
  float* P = (float*)d_out;
  char* ws = (char*)d_ws;
  float* aG  = (float*)(ws + 8192);
  float* bvG = (float*)(ws + 532480);

  embed_kernel<<<256, 512, 0, stream>>>(emb_in, maskp, emb_out, pad, pos,
                                        Win, bin, Wout, bout, aG, bvG, ws);
  sinkhorn_main<<<256, 512, 0, stream>>>(P, ws);
}

// Round 19
// 24.325 us; speedup vs baseline: 1.2641x; 1.2641x over previous
//
#include <hip/hip_runtime.h>

#define EPS 1e-4f
#define INVN (1.0f/512.0f)

// Two kernels, both REGULAR launches (r17 verbatim — proven best at 24.4us;
// r16's fusion (+8us) and r18's register-prefetch staging (+6us) both lost A/Bs
// against this structure).
//  K1 embed (256 x 512, register-tiled, r14 staging): weights+x/y LDS-staged in
//     per-chunk load->write order (compiler pipelines chunks), 8 dh-waves,
//     2-node x 4-m x 32-d tile -> aG, bvG (plain stores; dispatch boundary
//     provides coherence). Block 0 zeroes K2's barrier slots.
//  K2 sinkhorn (256 x 512, ONE barrier): cost->K_sh + block-local S estimate ->
//     exp+u0+colparts -> bar -> v1 -> P = u0*K*v1.
//     S-barrier eliminated via row-rescaling invariance: P = diag(u) K diag(v) is
//     EXACTLY invariant to row rescalings of K (u0 absorbs them), so each row-block
//     uses S_est = 32 x (own 16x512 C-sum); only within-row C deviation couples
//     (|dP| ~ 5e-10 << 4.9e-8 slack). Verified bit-identical absmax (r17).
//
// ws layout (bytes):
//   [0, 2048)         barrier one-shot slots (zeroed by K1 blk0): batch b at 256*b,
//                     cnt @ +0, flag @ +128
//   [8192, 532480)    aG [4096][32] f32  == alias ==  parts_A [8][32][512]
//                     (aG last read in K2 phase a, before bar; parts_A written later)
//   [532480, 1056768) bvG [4096][32] f32  (read only in K2 phase a)

__device__ __forceinline__ void store_f32_cg(float* p, float v) {
  asm volatile("global_store_dword %0, %1, off sc0 sc1" :: "v"(p), "v"(v) : "memory");
}

// 8 float4 at 2048-byte row stride (k-slices of parts), one wait.
__device__ __forceinline__ void load8x4_s2k_cg(const float* p1, const float* p2, float4* o) {
  asm volatile(
      "global_load_dwordx4 %0, %8, off offset:-4096 sc0 sc1\n\t"
      "global_load_dwordx4 %1, %8, off offset:-2048 sc0 sc1\n\t"
      "global_load_dwordx4 %2, %8, off sc0 sc1\n\t"
      "global_load_dwordx4 %3, %8, off offset:2048 sc0 sc1\n\t"
      "global_load_dwordx4 %4, %9, off offset:-4096 sc0 sc1\n\t"
      "global_load_dwordx4 %5, %9, off offset:-2048 sc0 sc1\n\t"
      "global_load_dwordx4 %6, %9, off sc0 sc1\n\t"
      "global_load_dwordx4 %7, %9, off offset:2048 sc0 sc1\n\t"
      "s_waitcnt vmcnt(0)"
      : "=&v"(o[0]), "=&v"(o[1]), "=&v"(o[2]), "=&v"(o[3]),
        "=&v"(o[4]), "=&v"(o[5]), "=&v"(o[6]), "=&v"(o[7])
      : "v"(p1), "v"(p2)
      : "memory");
}

__device__ __forceinline__ void batch_barrier(int* cnt, int* flag) {
  asm volatile("s_waitcnt vmcnt(0)" ::: "memory");   // drain write-through stores to LLC
  __syncthreads();
  if (threadIdx.x == 0) {
    int prev = __hip_atomic_fetch_add(cnt, 1, __ATOMIC_RELAXED, __HIP_MEMORY_SCOPE_AGENT);
    if (prev == 31) {
      __hip_atomic_store(flag, 1, __ATOMIC_RELAXED, __HIP_MEMORY_SCOPE_AGENT);
    } else {
      while (__hip_atomic_load(flag, __ATOMIC_RELAXED, __HIP_MEMORY_SCOPE_AGENT) == 0) {}
    }
  }
  __syncthreads();
}

// ---- Kernel 1: embed GEMVs. 256 blocks x 512 threads, block = 16 nodes. (r14 verbatim)
__global__ void __launch_bounds__(512)
embed_kernel(const float* __restrict__ emb_in, const void* __restrict__ maskp,
             const float* __restrict__ emb_out, const float* __restrict__ pad,
             const float* __restrict__ pos, const float* __restrict__ Win,
             const float* __restrict__ bin, const float* __restrict__ Wout,
             const float* __restrict__ bout,
             float* __restrict__ aG, float* __restrict__ bvG,
             char* __restrict__ ws) {
  const int t = threadIdx.x, blk = blockIdx.x;
  __shared__ float Wo_lds[8192];        // Wout [256][32], 32 KB
  __shared__ float Wi_lds[8192];        // Win  [256][32], 32 KB
  __shared__ float x_lds[16 * 260];     // (emb_out+pos)[n][d], pad 260
  __shared__ float y_lds[16 * 260];     // (emb_in|pad)[n][d]
  __shared__ float red_lds[7 * 64 * 20];// dh-reduce, 35 KB, stride 20 (16B-aligned)
  __shared__ unsigned dsh[2];
  __shared__ int mv_sh[16];

  if (blk == 0) store_f32_cg((float*)(ws + 4 * t), 0.0f);  // t<512 covers [0,2048)
  if (t < 2) dsh[t] = 0u;

#pragma unroll
  for (int k = 0; k < 4; ++k) {
    int i4 = k * 512 + t;               // 0..2047
    ((float4*)Wo_lds)[i4] = ((const float4*)Wout)[i4];
    ((float4*)Wi_lds)[i4] = ((const float4*)Win)[i4];
  }
  {
    const float4* eo4 = (const float4*)(emb_out + (size_t)blk * 16 * 256);
    const float4* po4 = (const float4*)(pos + (size_t)((blk * 16) & 511) * 256);
#pragma unroll
    for (int k = 0; k < 2; ++k) {
      int i4 = k * 512 + t;             // 0..1023; n = i4>>6, dc = i4&63
      int n = i4 >> 6, dc = i4 & 63;
      float4 e = eo4[i4], p = po4[i4];
      *(float4*)&x_lds[n * 260 + dc * 4] =
          make_float4(e.x + p.x, e.y + p.y, e.z + p.z, e.w + p.w);
    }
  }
  __syncthreads();                      // dsh init visible
  if (t < 256) {
    // mask element-size detect on first 4096 bytes (dword-wise)
    uint4 x = ((const uint4*)maskp)[t];
    unsigned orb = (x.x | x.y | x.z | x.w) & 0xFFFFFF00u;
    unsigned orc = (x.y | x.w) & 0xFFu;
    if (orb) atomicOr(&dsh[0], 1u);
    if (orc) atomicOr(&dsh[1], 1u);
  }
  __syncthreads();
  if (t < 16) {
    int g = blk * 16 + t;
    int mv;
    if (dsh[0])      mv = ((const unsigned char*)maskp)[g];
    else if (dsh[1]) mv = ((const int*)maskp)[g];
    else             mv = (int)(((const long long*)maskp)[g] != 0);
    mv_sh[t] = mv;
  }
  __syncthreads();
  {
    const float4* ein4 = (const float4*)(emb_in + (size_t)blk * 16 * 256);
    const float4* pad4 = (const float4*)pad;
#pragma unroll
    for (int k = 0; k < 2; ++k) {
      int i4 = k * 512 + t;
      int n = i4 >> 6, dc = i4 & 63;
      *(float4*)&y_lds[n * 260 + dc * 4] = mv_sh[n] ? pad4[dc] : ein4[i4];
    }
  }
  __syncthreads();

  const int dh = t >> 6, lane = t & 63;
  const int np = lane >> 3, mq = lane & 7;
  const int dbase = dh * 32;
  float aA0[4] = {0,0,0,0}, aA1[4] = {0,0,0,0};
  float aB0[4] = {0,0,0,0}, aB1[4] = {0,0,0,0};
  const float* x0p = &x_lds[(2 * np) * 260 + dbase];
  const float* x1p = x0p + 260;
  const float* y0p = &y_lds[(2 * np) * 260 + dbase];
  const float* y1p = y0p + 260;
  const float* Wob = &Wo_lds[dbase * 32 + 4 * mq];
  const float* Wib = &Wi_lds[dbase * 32 + 4 * mq];
  for (int it = 0; it < 8; ++it) {
    int dd = it * 4;
    float4 x0 = *(const float4*)(x0p + dd);
    float4 x1 = *(const float4*)(x1p + dd);
    float4 y0 = *(const float4*)(y0p + dd);
    float4 y1 = *(const float4*)(y1p + dd);
#pragma unroll
    for (int j = 0; j < 4; ++j) {
      float4 wo = *(const float4*)(Wob + (dd + j) * 32);
      float4 wi = *(const float4*)(Wib + (dd + j) * 32);
      float xs0 = ((const float*)&x0)[j], xs1 = ((const float*)&x1)[j];
      float ys0 = ((const float*)&y0)[j], ys1 = ((const float*)&y1)[j];
#pragma unroll
      for (int q = 0; q < 4; ++q) {
        float woq = ((const float*)&wo)[q], wiq = ((const float*)&wi)[q];
        aA0[q] = fmaf(xs0, woq, aA0[q]);
        aA1[q] = fmaf(xs1, woq, aA1[q]);
        aB0[q] = fmaf(ys0, wiq, aB0[q]);
        aB1[q] = fmaf(ys1, wiq, aB1[q]);
      }
    }
  }
  __syncthreads();                      // all x/y/W reads done
  if (dh != 0) {
    float* rp = &red_lds[((dh - 1) * 64 + lane) * 20];
    *(float4*)&rp[0]  = *(float4*)&aA0[0];
    *(float4*)&rp[4]  = *(float4*)&aA1[0];
    *(float4*)&rp[8]  = *(float4*)&aB0[0];
    *(float4*)&rp[12] = *(float4*)&aB1[0];
  }
  __syncthreads();
  if (dh == 0) {
#pragma unroll
    for (int k = 0; k < 7; ++k) {       // add dh1..dh7 in d-order
      const float* rp = &red_lds[(k * 64 + lane) * 20];
      float4 pa0 = *(const float4*)&rp[0];
      float4 pa1 = *(const float4*)&rp[4];
      float4 pb0 = *(const float4*)&rp[8];
      float4 pb1 = *(const float4*)&rp[12];
      aA0[0] += pa0.x; aA0[1] += pa0.y; aA0[2] += pa0.z; aA0[3] += pa0.w;
      aA1[0] += pa1.x; aA1[1] += pa1.y; aA1[2] += pa1.z; aA1[3] += pa1.w;
      aB0[0] += pb0.x; aB0[1] += pb0.y; aB0[2] += pb0.z; aB0[3] += pb0.w;
      aB1[0] += pb1.x; aB1[1] += pb1.y; aB1[2] += pb1.z; aB1[3] += pb1.w;
    }
    float4 bo = *(const float4*)&bout[4 * mq];
    float4 bi = *(const float4*)&bin[4 * mq];
    const int g0 = blk * 16 + 2 * np;
    *(float4*)&aG[(size_t)g0 * 32 + 4 * mq] =
        make_float4(aA0[0] + bo.x, aA0[1] + bo.y, aA0[2] + bo.z, aA0[3] + bo.w);
    *(float4*)&aG[(size_t)(g0 + 1) * 32 + 4 * mq] =
        make_float4(aA1[0] + bo.x, aA1[1] + bo.y, aA1[2] + bo.z, aA1[3] + bo.w);
    *(float4*)&bvG[(size_t)g0 * 32 + 4 * mq] =
        make_float4(aB0[0] + bi.x, aB0[1] + bi.y, aB0[2] + bi.z, aB0[3] + bi.w);
    *(float4*)&bvG[(size_t)(g0 + 1) * 32 + 4 * mq] =
        make_float4(aB1[0] + bi.x, aB1[1] + bi.y, aB1[2] + bi.z, aB1[3] + bi.w);
  }
}

// ---- Kernel 2: cost + 1-iter Sinkhorn + P. 256 blocks x 512 threads. ONE barrier. ----
__global__ void __launch_bounds__(512)
sinkhorn_main(float* __restrict__ P, char* __restrict__ ws) {
  const int t = threadIdx.x;
  const int blk = blockIdx.x;
  const int b = blk & 7, loc = blk >> 3;
  const int r0 = loc * 16;
  const int w = t >> 6, lane = t & 63;

  int* cnts  = (int*)(ws + 256 * b);
  int* flags = (int*)(ws + 256 * b + 128);
  float* aG      = (float*)(ws + 8192);
  float* partsA  = (float*)(ws + 8192);
  float* bvG     = (float*)(ws + 532480);

  __shared__ float K_sh[16][512];
  __shared__ float scratch_sh[8][512];
  __shared__ float v_sh[512];
  __shared__ float a_sh[16][32];
  __shared__ float red_sh[8];
  __shared__ float sv_sh;

  // ---- Phase a: stage own a-rows + own bv column (plain cached loads; K1->K2
  //      dispatch boundary provides coherence) ----
  float bva[32];
  {
    const float4* bj = (const float4*)(bvG + ((size_t)(b * 512) + t) * 32);
    float4 bq0 = bj[0], bq1 = bj[1], bq2 = bj[2], bq3 = bj[3];
    float4 bq4 = bj[4], bq5 = bj[5], bq6 = bj[6], bq7 = bj[7];
    ((float*)a_sh)[t] = aG[(size_t)(b * 512 + r0) * 32 + t];
    bva[0]=bq0.x; bva[1]=bq0.y; bva[2]=bq0.z; bva[3]=bq0.w;
    bva[4]=bq1.x; bva[5]=bq1.y; bva[6]=bq1.z; bva[7]=bq1.w;
    bva[8]=bq2.x; bva[9]=bq2.y; bva[10]=bq2.z; bva[11]=bq2.w;
    bva[12]=bq3.x; bva[13]=bq3.y; bva[14]=bq3.z; bva[15]=bq3.w;
    bva[16]=bq4.x; bva[17]=bq4.y; bva[18]=bq4.z; bva[19]=bq4.w;
    bva[20]=bq5.x; bva[21]=bq5.y; bva[22]=bq5.z; bva[23]=bq5.w;
    bva[24]=bq6.x; bva[25]=bq6.y; bva[26]=bq6.z; bva[27]=bq6.w;
    bva[28]=bq7.x; bva[29]=bq7.y; bva[30]=bq7.z; bva[31]=bq7.w;
  }
  __syncthreads();

  // ---- Phase b: cost -> K_sh; BLOCK-LOCAL S estimate (row-rescaling invariance of
  //      diag(u) K diag(v) makes per-row-block S exactly absorbed by u0) ----
  {
    float csum = 0.f;
    for (int r = 0; r < 16; ++r) {
      const float4* ar4 = (const float4*)&a_sh[r][0];   // LDS broadcast reads
      float c0 = 0.f;
#pragma unroll
      for (int q = 0; q < 8; ++q) {
        float4 av = ar4[q];
        c0 += fabsf(av.x - bva[q * 4 + 0]) + fabsf(av.y - bva[q * 4 + 1])
            + fabsf(av.z - bva[q * 4 + 2]) + fabsf(av.w - bva[q * 4 + 3]);
      }
      K_sh[r][t] = c0;
      csum += c0;
    }
#pragma unroll
    for (int off = 1; off < 64; off <<= 1) csum += __shfl_xor(csum, off);
    if (lane == 0) red_sh[w] = csum;
    __syncthreads();
    if (t == 0) {
      float s = 0.f;
#pragma unroll
      for (int k = 0; k < 8; ++k) s += red_sh[k];
      sv_sh = -1.0f / (EPS * 32.0f * s);    // S_est = 32 x block sum
    }
  }
  __syncthreads();
  const float sv = sv_sh;

  float u_last[2];
  const int w2 = t >> 7, idx = t & 127;
  float* partrowA = partsA + ((size_t)(b * 32) + loc) * 512;
  const float* vpA1 = partsA + (size_t)b * 32 * 512 + (size_t)(w2 * 8) * 512 + idx * 4 + 1024;
  const float* vpA2 = vpA1 + 2048;

  // ---- Phase c: K = exp(C*sv), u0 (v==1), column partials -> parts_A ----
  {
    float colacc[8] = {0, 0, 0, 0, 0, 0, 0, 0};
#pragma unroll
    for (int rr = 0; rr < 2; ++rr) {
      int r = 2 * w + rr;
      float4 c0 = *(float4*)&K_sh[r][4 * lane];
      float4 c1 = *(float4*)&K_sh[r][256 + 4 * lane];
      float kv[8];
      kv[0] = __expf(c0.x * sv); kv[1] = __expf(c0.y * sv);
      kv[2] = __expf(c0.z * sv); kv[3] = __expf(c0.w * sv);
      kv[4] = __expf(c1.x * sv); kv[5] = __expf(c1.y * sv);
      kv[6] = __expf(c1.z * sv); kv[7] = __expf(c1.w * sv);
      *(float4*)&K_sh[r][4 * lane]       = make_float4(kv[0], kv[1], kv[2], kv[3]);
      *(float4*)&K_sh[r][256 + 4 * lane] = make_float4(kv[4], kv[5], kv[6], kv[7]);
      float s = kv[0] + kv[1] + kv[2] + kv[3] + kv[4] + kv[5] + kv[6] + kv[7];
#pragma unroll
      for (int off = 1; off < 64; off <<= 1) s += __shfl_xor(s, off);
      float uu = INVN / s;
      u_last[rr] = uu;
#pragma unroll
      for (int q = 0; q < 8; ++q) colacc[q] = fmaf(kv[q], uu, colacc[q]);
    }
    *(float4*)&scratch_sh[w][4 * lane]       = make_float4(colacc[0], colacc[1], colacc[2], colacc[3]);
    *(float4*)&scratch_sh[w][256 + 4 * lane] = make_float4(colacc[4], colacc[5], colacc[6], colacc[7]);
    __syncthreads();
    float s0 = 0.f;
#pragma unroll
    for (int k = 0; k < 8; ++k) s0 += scratch_sh[k][t];
    store_f32_cg(partrowA + t, s0);
  }
  batch_barrier(&cnts[0], &flags[0]);       // the ONLY barrier: parts_A ready

  // ---- Phase d: v1 from parts_A; P = u0 * K * v1 ----
  {
    float4 o[8];
    load8x4_s2k_cg(vpA1, vpA2, o);
    float4 acc = o[0];
    acc.x += o[1].x + o[2].x + o[3].x + o[4].x + o[5].x + o[6].x + o[7].x;
    acc.y += o[1].y + o[2].y + o[3].y + o[4].y + o[5].y + o[6].y + o[7].y;
    acc.z += o[1].z + o[2].z + o[3].z + o[4].z + o[5].z + o[6].z + o[7].z;
    acc.w += o[1].w + o[2].w + o[3].w + o[4].w + o[5].w + o[6].w + o[7].w;
    *(float4*)&scratch_sh[w2][4 * idx] = acc;
  }
  __syncthreads();
  v_sh[t] = INVN / (scratch_sh[0][t] + scratch_sh[1][t] + scratch_sh[2][t] + scratch_sh[3][t]);
  __syncthreads();
  {
    float4 v0 = *(float4*)&v_sh[4 * lane];
    float4 v1 = *(float4*)&v_sh[256 + 4 * lane];
#pragma unroll
    for (int rr = 0; rr < 2; ++rr) {
      int r = 2 * w + rr;
      float uu = u_last[rr];
      float4 k0 = *(float4*)&K_sh[r][4 * lane];
      float4 k1 = *(float4*)&K_sh[r][256 + 4 * lane];
      float4 o0 = make_float4(uu * k0.x * v0.x, uu * k0.y * v0.y,
                              uu * k0.z * v0.z, uu * k0.w * v0.w);
      float4 o1 = make_float4(uu * k1.x * v1.x, uu * k1.y * v1.y,
                              uu * k1.z * v1.z, uu * k1.w * v1.w);
      float* Prow = P + ((size_t)(b * 512) + r0 + r) * 512;
      *(float4*)(Prow + 4 * lane)       = o0;
      *(float4*)(Prow + 256 + 4 * lane) = o1;
    }
  }
}

extern "C" void kernel_launch(void* const* d_in, const int* in_sizes, int n_in,
                              void* d_out, int out_size, void* d_ws, size_t ws_size,
                              hipStream_t stream) {
  const float* emb_in  = (const float*)d_in[0];
  const void*  maskp   = d_in[1];
  const float* emb_out = (const float*)d_in[2];
  const float* pad     = (const float*)d_in[3];
  const float* pos     = (const float*)d_in[4];
  const float* Win     = (const float*)d_in[5];
  const float* bin     = (const float*)d_in[6];
  const float* Wout    = (const float*)d_in[7];
  const float* bout    = (const float*)d_in[8];
  float* P = (float*)d_out;
  char* ws = (char*)d_ws;
  float* aG  = (float*)(ws + 8192);
  float* bvG = (float*)(ws + 532480);

  embed_kernel<<<256, 512, 0, stream>>>(emb_in, maskp, emb_out, pad, pos,
                                        Win, bin, Wout, bout, aG, bvG, ws);
  sinkhorn_main<<<256, 512, 0, stream>>>(P, ws);
}